// Round 9
// baseline (84.183 us; speedup 1.0000x reference)
//
#include <hip/hip_runtime.h>

// Problem constants (from reference)
constexpr int Bn = 8, Hn = 1536, Wn = 2048;
constexpr int NUM_GTS = 64;
constexpr int PLANE   = Hn * Wn;            // 3145728 elements per batch plane
constexpr int GROUPS  = PLANE / 4;          // 786432 groups of 4 columns
constexpr int BLOCKS  = 1024;               // 4 blocks/CU, fully resident (round-6 winner)
constexpr int GSTRIDE = BLOCKS * 256;       // 262144 threads; 3 groups per thread
constexpr float INV_N = 1.0f / (float)((long long)Bn * PLANE);

typedef float v2f __attribute__((ext_vector_type(2)));

// CDNA packed f32: one issue slot per 2 elements.
__device__ __forceinline__ v2f pk_fma(v2f a, v2f b, v2f c) {
    v2f d;
    asm("v_pk_fma_f32 %0, %1, %2, %3" : "=v"(d) : "v"(a), "v"(b), "v"(c));
    return d;
}
__device__ __forceinline__ v2f pk_add(v2f a, v2f b) {
    v2f d;
    asm("v_pk_add_f32 %0, %1, %2" : "=v"(d) : "v"(a), "v"(b));
    return d;
}

// Degree-8 Taylor poly of g(x)=softplus(x)*sigmoid(x)^2 on [-1,1].
// Max abs err 1.3e-4 (threshold 4.7e-3 -> 30x slack worst-case).
__device__ __forceinline__ v2f g_poly2(v2f x) {
    const float c0 = 0.173286795f, c1 = 0.298286795f, c2 = 0.199571699f,
                c3 = 0.048059430f, c4 = -0.011126533f, c5 = -0.007670527f,
                c6 = 0.000523747f, c7 = 0.001047450f, c8 = 0.000015192f;
    v2f t = (v2f){c8, c8};
    t = pk_fma(t, x, (v2f){c7, c7});
    t = pk_fma(t, x, (v2f){c6, c6});
    t = pk_fma(t, x, (v2f){c5, c5});
    t = pk_fma(t, x, (v2f){c4, c4});
    t = pk_fma(t, x, (v2f){c3, c3});
    t = pk_fma(t, x, (v2f){c2, c2});
    t = pk_fma(t, x, (v2f){c1, c1});
    t = pk_fma(t, x, (v2f){c0, c0});
    return t;
}

// Column-mask for one pixel-group. Wave lies in a single row, so lane i tests
// box i's row interval and one ballot gives the per-row active-box mask.
__device__ __forceinline__ unsigned group_tbits(int r, int c0, int tly, int bry,
                                                const int* s_tlx, const int* s_brx) {
    const bool rowhit = (r >= tly - 1) && (r < bry);
    unsigned long long rowm = __ballot(rowhit);
    unsigned tb = 0u;
    while (rowm) {
        const int i = __ffsll((unsigned long long)rowm) - 1;
        rowm &= rowm - 1;
        int lo = s_tlx[i] - 1 - c0;
        int hi = s_brx[i] - c0;
        lo = lo < 0 ? 0 : lo;
        hi = hi > 4 ? 4 : hi;
        if (lo < hi) tb |= ((1u << hi) - (1u << lo));
    }
    return tb;
}

// Sum 32 elements (8 planes x 4 cols) of one group held in registers, packed.
__device__ __forceinline__ v2f group_sum2(const float4* v, unsigned tb, v2f acc2) {
    float sgn[4];
#pragma unroll
    for (int j = 0; j < 4; ++j)
        sgn[j] = (tb & (1u << j)) ? -1.0f : 1.0f;
    const v2f s01 = (v2f){sgn[0], sgn[1]}, s23 = (v2f){sgn[2], sgn[3]};
    const v2f n01 = (v2f){-2.0f * sgn[0], -2.0f * sgn[1]};
    const v2f n23 = (v2f){-2.0f * sgn[2], -2.0f * sgn[3]};
#pragma unroll
    for (int b = 0; b < Bn; ++b) {
        const v2f p01 = (v2f){v[b].x, v[b].y};
        const v2f p23 = (v2f){v[b].z, v[b].w};
        acc2 = pk_add(acc2, g_poly2(pk_fma(n01, p01, s01)));
        acc2 = pk_add(acc2, g_poly2(pk_fma(n23, p23, s23)));
    }
    return acc2;
}

#define LOADG(dst, gid)                                                        \
    do {                                                                       \
        const int _base = ((gid) >> 9) * Wn + (((gid) & 511) << 2);            \
        _Pragma("unroll")                                                      \
        for (int _b = 0; _b < Bn; ++_b)                                        \
            dst[_b] = *reinterpret_cast<const float4*>(depth + _base + _b * PLANE); \
    } while (0)

// Fused kernel: round-6 main body + last-block-done reduction.
// ws[0..1023] : per-block partials (agent-scope atomic store/load -> coherent
//               across XCDs; plain store + threadfence risked stale L2 reads).
// cnt         : completion counter, memset to 0 each call (stream-ordered) so
//               old == BLOCKS-1 identifies the TRUE last arrival. (Round-8 bug:
//               residue test on an un-reset counter fired EARLY, not last.)
__global__ __launch_bounds__(256) void depth_loss_kernel(
    const float* __restrict__ depth,
    const int*   __restrict__ bbox,
    float*       __restrict__ ws,
    unsigned*    __restrict__ cnt,
    float*       __restrict__ out)
{
    __shared__ int s_tlx[NUM_GTS], s_brx[NUM_GTS];
    const int tid = threadIdx.x;
    if (tid < NUM_GTS) {
        s_tlx[tid] = bbox[tid * 4 + 0];
        s_brx[tid] = bbox[tid * 4 + 2];
    }
    __syncthreads();

    const int lane = tid & 63;
    const int tly  = bbox[lane * 4 + 1];    // per-lane own box, for the ballot
    const int bry  = bbox[lane * 4 + 3];

    const int g0 = blockIdx.x * 256 + tid;
    const int g1 = g0 + GSTRIDE;
    const int g2 = g1 + GSTRIDE;

    // Software pipeline: two register tile buffers, 16 loads in flight at peak.
    float4 A[Bn], Bv[Bn];
    LOADG(A, g0);
    LOADG(Bv, g1);

    // Mask math overlaps with load latency.
    const unsigned tb0 = group_tbits(g0 >> 9, (g0 & 511) << 2, tly, bry, s_tlx, s_brx);
    const unsigned tb1 = group_tbits(g1 >> 9, (g1 & 511) << 2, tly, bry, s_tlx, s_brx);
    const unsigned tb2 = group_tbits(g2 >> 9, (g2 & 511) << 2, tly, bry, s_tlx, s_brx);

    v2f acc2 = (v2f){0.0f, 0.0f};
    acc2 = group_sum2(A, tb0, acc2);        // Bv in flight
    LOADG(A, g2);
    acc2 = group_sum2(Bv, tb1, acc2);       // A(g2) in flight
    acc2 = group_sum2(A, tb2, acc2);
    float acc = acc2.x + acc2.y;

    // Wave reduce, block reduce.
#pragma unroll
    for (int off = 32; off > 0; off >>= 1)
        acc += __shfl_down(acc, off, 64);

    __shared__ float s_part[4];
    __shared__ int   s_last;
    if (lane == 0) s_part[tid >> 6] = acc;
    __syncthreads();

    if (tid == 0) {
        const float part = s_part[0] + s_part[1] + s_part[2] + s_part[3];
        __hip_atomic_store(&ws[blockIdx.x], part,
                           __ATOMIC_RELEASE, __HIP_MEMORY_SCOPE_AGENT);
        const unsigned old = __hip_atomic_fetch_add(cnt, 1u,
                           __ATOMIC_ACQ_REL, __HIP_MEMORY_SCOPE_AGENT);
        s_last = (old == (unsigned)(BLOCKS - 1));   // true last arrival
    }
    __syncthreads();

    if (s_last) {
        // Coherent (agent-scope acquire) loads of all partials; fixed
        // summation order -> bitwise-deterministic result.
        float s = 0.0f;
#pragma unroll
        for (int k = 0; k < 4; ++k)
            s += __hip_atomic_load(&ws[tid + k * 256],
                                   __ATOMIC_ACQUIRE, __HIP_MEMORY_SCOPE_AGENT);
#pragma unroll
        for (int off = 32; off > 0; off >>= 1)
            s += __shfl_down(s, off, 64);
        if (lane == 0) s_part[tid >> 6] = s;
        __syncthreads();
        if (tid == 0)
            out[0] = (s_part[0] + s_part[1] + s_part[2] + s_part[3]) * INV_N;
    }
}

extern "C" void kernel_launch(void* const* d_in, const int* in_sizes, int n_in,
                              void* d_out, int out_size, void* d_ws, size_t ws_size,
                              hipStream_t stream) {
    const float* depth = (const float*)d_in[0];
    const int*   bbox  = (const int*)d_in[1];
    float*       out   = (float*)d_out;
    float*       ws    = (float*)d_ws;
    unsigned*    cnt   = (unsigned*)((char*)d_ws + BLOCKS * sizeof(float));

    hipMemsetAsync(cnt, 0, sizeof(unsigned), stream);   // counter = 0 each call
    depth_loss_kernel<<<BLOCKS, 256, 0, stream>>>(depth, bbox, ws, cnt, out);
}

// Round 10
// 28.925 us; speedup vs baseline: 2.9104x; 2.9104x over previous
//
#include <hip/hip_runtime.h>

// Problem constants (from reference)
constexpr int Bn = 8, Hn = 1536, Wn = 2048;
constexpr int NUM_GTS = 64;
constexpr int PLANE   = Hn * Wn;            // 3145728 elements per batch plane
constexpr int GROUPS  = PLANE / 4;          // 786432 groups of 4 columns
constexpr int BLOCKS  = 1024;               // 4 blocks/CU, fully resident
constexpr int GSTRIDE = BLOCKS * 256;       // 262144 threads; 3 groups per thread
constexpr float INV_N = 1.0f / (float)((long long)Bn * PLANE);

typedef float v2f __attribute__((ext_vector_type(2)));

// CDNA packed f32: one issue slot per 2 elements.
__device__ __forceinline__ v2f pk_fma(v2f a, v2f b, v2f c) {
    v2f d;
    asm("v_pk_fma_f32 %0, %1, %2, %3" : "=v"(d) : "v"(a), "v"(b), "v"(c));
    return d;
}
__device__ __forceinline__ v2f pk_add(v2f a, v2f b) {
    v2f d;
    asm("v_pk_add_f32 %0, %1, %2" : "=v"(d) : "v"(a), "v"(b));
    return d;
}

// Degree-8 Taylor poly of g(x)=softplus(x)*sigmoid(x)^2 on [-1,1].
// Max abs err 1.3e-4 (threshold 4.7e-3 -> 30x slack worst-case).
__device__ __forceinline__ v2f g_poly2(v2f x) {
    const float c0 = 0.173286795f, c1 = 0.298286795f, c2 = 0.199571699f,
                c3 = 0.048059430f, c4 = -0.011126533f, c5 = -0.007670527f,
                c6 = 0.000523747f, c7 = 0.001047450f, c8 = 0.000015192f;
    v2f t = (v2f){c8, c8};
    t = pk_fma(t, x, (v2f){c7, c7});
    t = pk_fma(t, x, (v2f){c6, c6});
    t = pk_fma(t, x, (v2f){c5, c5});
    t = pk_fma(t, x, (v2f){c4, c4});
    t = pk_fma(t, x, (v2f){c3, c3});
    t = pk_fma(t, x, (v2f){c2, c2});
    t = pk_fma(t, x, (v2f){c1, c1});
    t = pk_fma(t, x, (v2f){c0, c0});
    return t;
}

// Column-mask for one pixel-group. Wave lies in a single row, so lane i tests
// box i's row interval and one ballot gives the per-row active-box mask.
__device__ __forceinline__ unsigned group_tbits(int r, int c0, int tly, int bry,
                                                const int* s_tlx, const int* s_brx) {
    const bool rowhit = (r >= tly - 1) && (r < bry);
    unsigned long long rowm = __ballot(rowhit);
    unsigned tb = 0u;
    while (rowm) {
        const int i = __ffsll((unsigned long long)rowm) - 1;
        rowm &= rowm - 1;
        int lo = s_tlx[i] - 1 - c0;
        int hi = s_brx[i] - c0;
        lo = lo < 0 ? 0 : lo;
        hi = hi > 4 ? 4 : hi;
        if (lo < hi) tb |= ((1u << hi) - (1u << lo));
    }
    return tb;
}

// Sum 32 elements (8 planes x 4 cols) of one group held in registers, packed.
__device__ __forceinline__ v2f group_sum2(const float4* v, unsigned tb, v2f acc2) {
    float sgn[4];
#pragma unroll
    for (int j = 0; j < 4; ++j)
        sgn[j] = (tb & (1u << j)) ? -1.0f : 1.0f;
    const v2f s01 = (v2f){sgn[0], sgn[1]}, s23 = (v2f){sgn[2], sgn[3]};
    const v2f n01 = (v2f){-2.0f * sgn[0], -2.0f * sgn[1]};
    const v2f n23 = (v2f){-2.0f * sgn[2], -2.0f * sgn[3]};
#pragma unroll
    for (int b = 0; b < Bn; ++b) {
        const v2f p01 = (v2f){v[b].x, v[b].y};
        const v2f p23 = (v2f){v[b].z, v[b].w};
        acc2 = pk_add(acc2, g_poly2(pk_fma(n01, p01, s01)));
        acc2 = pk_add(acc2, g_poly2(pk_fma(n23, p23, s23)));
    }
    return acc2;
}

#define LOADG(dst, gid)                                                        \
    do {                                                                       \
        const int _base = ((gid) >> 9) * Wn + (((gid) & 511) << 2);            \
        _Pragma("unroll")                                                      \
        for (int _b = 0; _b < Bn; ++_b)                                        \
            dst[_b] = *reinterpret_cast<const float4*>(depth + _base + _b * PLANE); \
    } while (0)

// Round-6 structure, but with THREE register buffers and a scheduling barrier
// so ALL 24 loads are issued before any consume. (Round-9 counters exposed
// VGPR=52 on the identical body: the compiler was sinking loads and the
// "double buffer" never existed in the emitted code. sched_barrier(0) pins
// the loads above the compute; launch_bounds(256,4) caps VGPR at 128 so
// 16 waves/CU survive.)
__global__ __launch_bounds__(256, 4) void depth_loss_kernel(
    const float* __restrict__ depth,
    const int*   __restrict__ bbox,
    float*       __restrict__ ws)
{
    __shared__ int s_tlx[NUM_GTS], s_brx[NUM_GTS];
    const int tid = threadIdx.x;
    if (tid < NUM_GTS) {
        s_tlx[tid] = bbox[tid * 4 + 0];
        s_brx[tid] = bbox[tid * 4 + 2];
    }
    __syncthreads();

    const int lane = tid & 63;
    const int tly  = bbox[lane * 4 + 1];    // per-lane own box, for the ballot
    const int bry  = bbox[lane * 4 + 3];

    const int g0 = blockIdx.x * 256 + tid;
    const int g1 = g0 + GSTRIDE;
    const int g2 = g1 + GSTRIDE;

    // Issue ALL 24 loads, then forbid the scheduler from sinking them.
    float4 A[Bn], Bv[Bn], C[Bn];
    LOADG(A, g0);
    LOADG(Bv, g1);
    LOADG(C, g2);
    __builtin_amdgcn_sched_barrier(0);

    // Mask math executes while the 24 loads are in flight.
    const unsigned tb0 = group_tbits(g0 >> 9, (g0 & 511) << 2, tly, bry, s_tlx, s_brx);
    const unsigned tb1 = group_tbits(g1 >> 9, (g1 & 511) << 2, tly, bry, s_tlx, s_brx);
    const unsigned tb2 = group_tbits(g2 >> 9, (g2 & 511) << 2, tly, bry, s_tlx, s_brx);

    v2f acc2 = (v2f){0.0f, 0.0f};
    acc2 = group_sum2(A, tb0, acc2);
    acc2 = group_sum2(Bv, tb1, acc2);
    acc2 = group_sum2(C, tb2, acc2);
    float acc = acc2.x + acc2.y;

    // Wave reduce, block reduce, one ws write per block. No atomics.
#pragma unroll
    for (int off = 32; off > 0; off >>= 1)
        acc += __shfl_down(acc, off, 64);

    __shared__ float s_part[4];
    if (lane == 0) s_part[tid >> 6] = acc;
    __syncthreads();
    if (tid == 0)
        ws[blockIdx.x] = s_part[0] + s_part[1] + s_part[2] + s_part[3];
}

// Single-wave reduce of 1024 partials: 16 independent loads in flight, no LDS.
__global__ __launch_bounds__(64) void reduce_kernel(
    const float* __restrict__ ws,
    float*       __restrict__ out)
{
    const int tid = threadIdx.x;
    float s = 0.0f;
#pragma unroll
    for (int i = 0; i < 16; ++i)
        s += ws[tid + i * 64];
#pragma unroll
    for (int off = 32; off > 0; off >>= 1)
        s += __shfl_down(s, off, 64);
    if (tid == 0)
        out[0] = s * INV_N;
}

extern "C" void kernel_launch(void* const* d_in, const int* in_sizes, int n_in,
                              void* d_out, int out_size, void* d_ws, size_t ws_size,
                              hipStream_t stream) {
    const float* depth = (const float*)d_in[0];
    const int*   bbox  = (const int*)d_in[1];
    float*       out   = (float*)d_out;
    float*       ws    = (float*)d_ws;

    depth_loss_kernel<<<BLOCKS, 256, 0, stream>>>(depth, bbox, ws);
    reduce_kernel<<<1, 64, 0, stream>>>(ws, out);
}

// Round 11
// 24.775 us; speedup vs baseline: 3.3979x; 1.1675x over previous
//
#include <hip/hip_runtime.h>

// Problem constants (from reference)
constexpr int Bn = 8, Hn = 1536, Wn = 2048;
constexpr int NUM_GTS = 64;
constexpr int PLANE   = Hn * Wn;            // 3145728 elements per batch plane
constexpr int GROUPS  = PLANE / 4;          // 786432 groups of 4 columns
constexpr int BLOCKS  = 1024;               // 4 blocks/CU, fully resident
constexpr int GSTRIDE = BLOCKS * 256;       // 262144 threads; 3 groups per thread
constexpr float INV_N = 1.0f / (float)((long long)Bn * PLANE);

typedef float v2f __attribute__((ext_vector_type(2)));

// CDNA packed f32: one issue slot per 2 elements.
__device__ __forceinline__ v2f pk_fma(v2f a, v2f b, v2f c) {
    v2f d;
    asm("v_pk_fma_f32 %0, %1, %2, %3" : "=v"(d) : "v"(a), "v"(b), "v"(c));
    return d;
}
__device__ __forceinline__ v2f pk_add(v2f a, v2f b) {
    v2f d;
    asm("v_pk_add_f32 %0, %1, %2" : "=v"(d) : "v"(a), "v"(b));
    return d;
}

// Degree-8 Taylor poly of g(x)=softplus(x)*sigmoid(x)^2 on [-1,1].
// Max abs err 1.3e-4 (threshold 4.7e-3 -> 30x slack worst-case).
__device__ __forceinline__ v2f g_poly2(v2f x) {
    const float c0 = 0.173286795f, c1 = 0.298286795f, c2 = 0.199571699f,
                c3 = 0.048059430f, c4 = -0.011126533f, c5 = -0.007670527f,
                c6 = 0.000523747f, c7 = 0.001047450f, c8 = 0.000015192f;
    v2f t = (v2f){c8, c8};
    t = pk_fma(t, x, (v2f){c7, c7});
    t = pk_fma(t, x, (v2f){c6, c6});
    t = pk_fma(t, x, (v2f){c5, c5});
    t = pk_fma(t, x, (v2f){c4, c4});
    t = pk_fma(t, x, (v2f){c3, c3});
    t = pk_fma(t, x, (v2f){c2, c2});
    t = pk_fma(t, x, (v2f){c1, c1});
    t = pk_fma(t, x, (v2f){c0, c0});
    return t;
}

// Column-mask for one pixel-group. Wave lies in a single row, so lane i tests
// box i's row interval and one ballot gives the per-row active-box mask.
__device__ __forceinline__ unsigned group_tbits(int r, int c0, int tly, int bry,
                                                const int* s_tlx, const int* s_brx) {
    const bool rowhit = (r >= tly - 1) && (r < bry);
    unsigned long long rowm = __ballot(rowhit);
    unsigned tb = 0u;
    while (rowm) {
        const int i = __ffsll((unsigned long long)rowm) - 1;
        rowm &= rowm - 1;
        int lo = s_tlx[i] - 1 - c0;
        int hi = s_brx[i] - c0;
        lo = lo < 0 ? 0 : lo;
        hi = hi > 4 ? 4 : hi;
        if (lo < hi) tb |= ((1u << hi) - (1u << lo));
    }
    return tb;
}

// PLANE-SEQUENTIAL sweep (the round-11 change): instead of bursting all 8
// planes per group (8 concurrent 12MB-strided streams per wave -> ~2048
// device-wide -> DRAM row-buffer thrash, measured ~4.6 TB/s vs 6.3 copy
// ceiling), iterate planes as 8 time phases. Phase b loads the 3 groups of
// plane b (double-buffered, prefetching plane b+1 while computing plane b).
// At any instant the device reads ~1 plane = 3 contiguous windows -> DRAM
// row locality like a plain copy.
__global__ __launch_bounds__(256) void depth_loss_kernel(
    const float* __restrict__ depth,
    const int*   __restrict__ bbox,
    float*       __restrict__ ws)
{
    __shared__ int s_tlx[NUM_GTS], s_brx[NUM_GTS];
    const int tid = threadIdx.x;
    if (tid < NUM_GTS) {
        s_tlx[tid] = bbox[tid * 4 + 0];
        s_brx[tid] = bbox[tid * 4 + 2];
    }
    __syncthreads();

    const int lane = tid & 63;
    const int tly  = bbox[lane * 4 + 1];    // per-lane own box, for the ballot
    const int bry  = bbox[lane * 4 + 3];

    const int g0 = blockIdx.x * 256 + tid;
    const int g1 = g0 + GSTRIDE;
    const int g2 = g1 + GSTRIDE;

    // Per-group element bases (gid*4 = r*Wn + c0 exactly).
    const float* p0 = depth + (g0 << 2);
    const float* p1 = depth + (g1 << 2);
    const float* p2 = depth + (g2 << 2);

    // Per-group sign constants, computed once (masks are plane-independent).
    const unsigned tbs[3] = {
        group_tbits(g0 >> 9, (g0 & 511) << 2, tly, bry, s_tlx, s_brx),
        group_tbits(g1 >> 9, (g1 & 511) << 2, tly, bry, s_tlx, s_brx),
        group_tbits(g2 >> 9, (g2 & 511) << 2, tly, bry, s_tlx, s_brx)};
    v2f s01[3], s23[3], n01[3], n23[3];
#pragma unroll
    for (int j = 0; j < 3; ++j) {
        const float sg0 = (tbs[j] & 1u) ? -1.0f : 1.0f;
        const float sg1 = (tbs[j] & 2u) ? -1.0f : 1.0f;
        const float sg2 = (tbs[j] & 4u) ? -1.0f : 1.0f;
        const float sg3 = (tbs[j] & 8u) ? -1.0f : 1.0f;
        s01[j] = (v2f){sg0, sg1};
        s23[j] = (v2f){sg2, sg3};
        n01[j] = (v2f){-2.0f * sg0, -2.0f * sg1};
        n23[j] = (v2f){-2.0f * sg2, -2.0f * sg3};
    }

#define LOAD3(dst, b)                                                          \
    do {                                                                       \
        dst[0] = *reinterpret_cast<const float4*>(p0 + (b) * PLANE);           \
        dst[1] = *reinterpret_cast<const float4*>(p1 + (b) * PLANE);           \
        dst[2] = *reinterpret_cast<const float4*>(p2 + (b) * PLANE);           \
    } while (0)

    float4 cur[3], nxt[3];
    LOAD3(cur, 0);

    v2f acc2 = (v2f){0.0f, 0.0f};
#pragma unroll
    for (int b = 0; b < Bn; ++b) {
        if (b + 1 < Bn) LOAD3(nxt, b + 1);      // prefetch next plane
#pragma unroll
        for (int j = 0; j < 3; ++j) {
            const v2f q01 = (v2f){cur[j].x, cur[j].y};
            const v2f q23 = (v2f){cur[j].z, cur[j].w};
            acc2 = pk_add(acc2, g_poly2(pk_fma(n01[j], q01, s01[j])));
            acc2 = pk_add(acc2, g_poly2(pk_fma(n23[j], q23, s23[j])));
        }
#pragma unroll
        for (int j = 0; j < 3; ++j) cur[j] = nxt[j];
    }
    float acc = acc2.x + acc2.y;

    // Wave reduce, block reduce, one ws write per block. No atomics.
#pragma unroll
    for (int off = 32; off > 0; off >>= 1)
        acc += __shfl_down(acc, off, 64);

    __shared__ float s_part[4];
    if (lane == 0) s_part[tid >> 6] = acc;
    __syncthreads();
    if (tid == 0)
        ws[blockIdx.x] = s_part[0] + s_part[1] + s_part[2] + s_part[3];
}

// Single-wave reduce of 1024 partials: 16 independent loads in flight, no LDS.
__global__ __launch_bounds__(64) void reduce_kernel(
    const float* __restrict__ ws,
    float*       __restrict__ out)
{
    const int tid = threadIdx.x;
    float s = 0.0f;
#pragma unroll
    for (int i = 0; i < 16; ++i)
        s += ws[tid + i * 64];
#pragma unroll
    for (int off = 32; off > 0; off >>= 1)
        s += __shfl_down(s, off, 64);
    if (tid == 0)
        out[0] = s * INV_N;
}

extern "C" void kernel_launch(void* const* d_in, const int* in_sizes, int n_in,
                              void* d_out, int out_size, void* d_ws, size_t ws_size,
                              hipStream_t stream) {
    const float* depth = (const float*)d_in[0];
    const int*   bbox  = (const int*)d_in[1];
    float*       out   = (float*)d_out;
    float*       ws    = (float*)d_ws;

    depth_loss_kernel<<<BLOCKS, 256, 0, stream>>>(depth, bbox, ws);
    reduce_kernel<<<1, 64, 0, stream>>>(ws, out);
}